// Round 19
// baseline (136.964 us; speedup 1.0000x reference)
//
#include <hip/hip_runtime.h>
#include <hip/hip_bf16.h>

#define RSH 7                  // 128 rows per bucket
#define RPB (1 << RSH)
#define CSH 17                 // col bits in packed record (N < 131072)
#define CMASK ((1 << CSH) - 1)
#define CHUNK_E 8192           // edges per chunk block
#define CAP 4096               // max records per bucket (mean ~2046, 45 sigma)
#define NBMAX 1024

typedef __attribute__((ext_vector_type(8))) _Float16 f16x8;
typedef __attribute__((ext_vector_type(2))) _Float16 f16x2;
typedef __attribute__((ext_vector_type(4))) float f32x4;

__device__ __forceinline__ unsigned int pack2h(float a, float b) {
    union { _Float16 h[2]; unsigned int u; } c;
    c.h[0] = (_Float16)a; c.h[1] = (_Float16)b;
    return c.u;
}
__device__ __forceinline__ unsigned short f2h_bits(float f) {
    union { _Float16 h; unsigned short u; } c;
    c.h = (_Float16)f;
    return c.u;
}

// ---------- 0. W pre-convert: build the swizzled f16 LDS image once ----------
__global__ __launch_bounds__(256) void wsplit(
    const float* __restrict__ Wg, unsigned int* __restrict__ WhiG)
{
    int task = blockIdx.x * 256 + threadIdx.x;   // 2048 tasks
    if (task >= 2048) return;
    int n  = task & 127;
    int k0 = (task >> 7) * 8;
    unsigned int hi[4];
    #pragma unroll
    for (int j = 0; j < 4; ++j) {
        float w0 = Wg[(size_t)(k0 + 2*j)     * 128 + n];
        float w1 = Wg[(size_t)(k0 + 2*j + 1) * 128 + n];
        hi[j] = pack2h(w0, w1);
    }
    int byte = (k0 * 2) ^ ((n & 7) << 4);
    *(uint4*)((char*)WhiG + n * 256 + byte) = make_uint4(hi[0], hi[1], hi[2], hi[3]);
}

// ---------- 1. fused: GEMM via single-f16 MFMA + chunk_hist ----------
__global__ __launch_bounds__(512) void gemm_hist(
    const float* __restrict__ H, const unsigned int* __restrict__ WhiG,
    unsigned short* __restrict__ Hpb, int N,
    const int* __restrict__ row, unsigned short* __restrict__ Ht,
    int E, int nchunk, int nb2, int gemmBlocks)
{
    __shared__ unsigned short Ahi[128 * 128];   // 32 KB
    __shared__ unsigned short Whi[128 * 128];   // 32 KB (pre-converted image)
    const int tid = threadIdx.x;

    if (blockIdx.x >= gemmBlocks) {
        int* cnt = (int*)Ahi;
        const int c = blockIdx.x - gemmBlocks;
        for (int i = tid; i < nb2; i += 512) cnt[i] = 0;
        __syncthreads();
        const int e0 = c * CHUNK_E;
        const int e1 = min(e0 + CHUNK_E, E);
        for (int e = e0 + tid; e < e1; e += 512)
            atomicAdd(&cnt[row[e] >> RSH], 1);
        __syncthreads();
        for (int i = tid; i < nb2; i += 512)
            Ht[(size_t)i * nchunk + c] = (unsigned short)cnt[i];
        return;
    }

    const int rbase = blockIdx.x * 128;

    // stage pre-converted W: verbatim 32KB copy
    #pragma unroll
    for (int i = 0; i < 4; ++i) {
        int idx = tid + 512 * i;               // 2048 uint4
        ((uint4*)Whi)[idx] = ((const uint4*)WhiG)[idx];
    }
    // stage H rows as f16
    #pragma unroll
    for (int i = 0; i < 8; ++i) {
        int flat = tid + 512 * i;          // 4096 float4-tasks
        int rr = flat >> 5;
        int c4  = (flat & 31) * 4;
        float4 h = make_float4(0.f, 0.f, 0.f, 0.f);
        if (rbase + rr < N)
            h = *(const float4*)&H[(size_t)(rbase + rr) * 128 + c4];
        uint2 vh;
        vh.x = pack2h(h.x, h.y);
        vh.y = pack2h(h.z, h.w);
        int byte = (c4 * 2) ^ ((rr & 7) << 4);
        *(uint2*)((char*)Ahi + rr * 256 + byte) = vh;
    }
    __syncthreads();

    const int wid = tid >> 6, lane = tid & 63;
    const int wm = wid >> 1, wn = wid & 1;
    const int lr = lane & 15, lg = lane >> 4;
    f32x4 acc[2][4] = {};

    #pragma unroll
    for (int ks = 0; ks < 4; ++ks) {
        const int kb = ks * 64 + lg * 16;
        f16x8 ahi[2];
        #pragma unroll
        for (int mi = 0; mi < 2; ++mi) {
            int rr = wm * 32 + mi * 16 + lr;
            int sw = kb ^ ((rr & 7) << 4);
            ahi[mi] = *(const f16x8*)((char*)Ahi + rr * 256 + sw);
        }
        #pragma unroll
        for (int nf = 0; nf < 4; ++nf) {
            int n = wn * 64 + nf * 16 + lr;
            int sw = kb ^ ((n & 7) << 4);
            f16x8 bhi = *(const f16x8*)((char*)Whi + n * 256 + sw);
            #pragma unroll
            for (int mi = 0; mi < 2; ++mi)
                acc[mi][nf] = __builtin_amdgcn_mfma_f32_16x16x32_f16(ahi[mi], bhi, acc[mi][nf], 0, 0, 0);
        }
    }

    #pragma unroll
    for (int mi = 0; mi < 2; ++mi) {
        #pragma unroll
        for (int nf = 0; nf < 4; ++nf) {
            int col = wn * 64 + nf * 16 + lr;
            #pragma unroll
            for (int i = 0; i < 4; ++i) {
                int rr = rbase + wm * 32 + mi * 16 + lg * 4 + i;
                if (rr < N)
                    Hpb[(size_t)rr * 128 + col] = f2h_bits(acc[mi][nf][i]);
            }
        }
    }
}

// ---------- 2b. per-bucket scan over chunks ----------
__global__ __launch_bounds__(256) void bucket_scan(
    const unsigned short* __restrict__ Ht, unsigned short* __restrict__ rel,
    int* __restrict__ totals, int nchunk)
{
    __shared__ int s[256];
    const int b = blockIdx.x, tid = threadIdx.x;
    int v = (tid < nchunk) ? (int)Ht[(size_t)b * nchunk + tid] : 0;
    s[tid] = v;
    __syncthreads();
    for (int d = 1; d < 256; d <<= 1) {
        int t = (tid >= d) ? s[tid - d] : 0;
        __syncthreads();
        s[tid] += t;
        __syncthreads();
    }
    if (tid < nchunk) rel[(size_t)b * nchunk + tid] = (unsigned short)(s[tid] - v);
    if (tid == 255) totals[b] = s[255];
}

// ---------- 2c. scan bucket totals -> bucketptr ----------
__global__ __launch_bounds__(1024) void bucket_ptr_scan(
    const int* __restrict__ totals, int* __restrict__ bucketptr, int nb2)
{
    __shared__ int s[1024];
    const int tid = threadIdx.x;
    int v = (tid < nb2) ? totals[tid] : 0;
    s[tid] = v;
    __syncthreads();
    for (int d = 1; d < 1024; d <<= 1) {
        int t = (tid >= d) ? s[tid - d] : 0;
        __syncthreads();
        s[tid] += t;
        __syncthreads();
    }
    if (tid < nb2) bucketptr[tid] = s[tid] - v;
    if (tid == nb2 - 1) bucketptr[nb2] = s[tid];
}

// ---------- 2d. single-pass scatter: exact per-chunk offsets, 8KB LDS ----------
__global__ __launch_bounds__(256) void chunk_scatter(
    const int* __restrict__ row, const int* __restrict__ col,
    const unsigned short* __restrict__ rel, const int* __restrict__ bucketptr,
    int* __restrict__ colsort, int E, int nchunk, int nb2)
{
    __shared__ int cur[NBMAX];
    __shared__ int gb[NBMAX];
    const int tid = threadIdx.x;
    const int c = blockIdx.x;
    const int e0 = c * CHUNK_E;
    const int tot = min(CHUNK_E, E - e0);

    for (int b = tid; b < nb2; b += 256) {
        cur[b] = 0;
        gb[b] = bucketptr[b] + (int)rel[(size_t)b * nchunk + c];
    }
    __syncthreads();

    for (int j = tid; j < tot; j += 256) {
        int r = row[e0 + j], cc = col[e0 + j];
        int b = r >> RSH;
        int p = atomicAdd(&cur[b], 1);
        colsort[gb[b] + p] = ((r & (RPB - 1)) << CSH) | cc;
    }
}

// ---------- 3. fused bucket sort + score + softmax + aggregate ----------
// One block per bucket (512 thr, 8 waves, 32 groups of 16 lanes).
// Phase 1: in-LDS counting sort of the bucket's packed records -> ord[], rowoff[].
// Phase 2: each 16-lane group owns whole rows (4 rows, stride 32); per-edge
// chain identical to the settled R16 aggregate (fdot2, masked unroll-2).
union F16x8U {
    uint4 v;
    f16x2 p[4];
    _Float16 h[8];
};

__device__ __forceinline__ float dot8(const f16x2* a, const F16x8U& b) {
#if __has_builtin(__builtin_amdgcn_fdot2)
    float d = __builtin_amdgcn_fdot2(a[0], b.p[0], 0.f, false);
    d = __builtin_amdgcn_fdot2(a[1], b.p[1], d, false);
    d = __builtin_amdgcn_fdot2(a[2], b.p[2], d, false);
    d = __builtin_amdgcn_fdot2(a[3], b.p[3], d, false);
    return d;
#else
    float d = 0.f;
    #pragma unroll
    for (int k = 0; k < 8; ++k)
        d = fmaf((float)a[k >> 1][k & 1], (float)b.h[k], d);
    return d;
#endif
}

__global__ __launch_bounds__(512) void bucket_aggregate(
    const unsigned short* __restrict__ Hpb, const int* __restrict__ bucketptr,
    const int* __restrict__ colsort, const float* __restrict__ bias,
    float* __restrict__ out, int N)
{
    __shared__ int ord[CAP];           // 16 KB
    __shared__ int rowoff[RPB + 1];
    __shared__ int rcur[RPB];
    __shared__ int sc[RPB];
    const int b = blockIdx.x, tid = threadIdx.x;
    const int rbase = b << RSH;
    const int s0 = bucketptr[b];
    const int cnt = bucketptr[b + 1] - s0;

    // --- phase 1: counting sort by local row ---
    if (tid < RPB) rcur[tid] = 0;
    __syncthreads();
    for (int j = tid; j < cnt; j += 512)
        atomicAdd(&rcur[colsort[s0 + j] >> CSH], 1);
    __syncthreads();

    int v = (tid < RPB) ? rcur[tid] : 0;
    if (tid < RPB) sc[tid] = v;
    __syncthreads();
    for (int dd = 1; dd < RPB; dd <<= 1) {
        int t = (tid >= dd && tid < RPB) ? sc[tid - dd] : 0;
        __syncthreads();
        if (tid < RPB) sc[tid] += t;
        __syncthreads();
    }
    if (tid < RPB) {
        int ex = sc[tid] - v;
        rowoff[tid] = ex;
        rcur[tid] = ex;
    }
    if (tid == 0) rowoff[RPB] = cnt;
    __syncthreads();

    for (int j = tid; j < cnt; j += 512) {
        int rec = colsort[s0 + j];
        int p = atomicAdd(&rcur[rec >> CSH], 1);
        ord[p] = rec & CMASK;
    }
    __syncthreads();

    // --- phase 2: aggregate; group gi owns rows gi, gi+32, gi+64, gi+96 ---
    const int lane = tid & 63;
    const int wv = tid >> 6;
    const int g = lane >> 4;
    const int d = lane & 15;
    const int gi = wv * 4 + g;

    const float4* bp = (const float4*)&bias[d * 8];
    const float4 b0 = bp[0], b1 = bp[1];

    for (int lr = gi; lr < RPB; lr += 32) {
        const int r = rbase + lr;
        if (r >= N) continue;

        F16x8U hru;
        hru.v = *(const uint4*)&Hpb[(size_t)r * 128 + d * 8];
        f16x2 hr2[4] = {hru.p[0], hru.p[1], hru.p[2], hru.p[3]};

        float acc[8] = {0.f,0.f,0.f,0.f,0.f,0.f,0.f,0.f};
        float den = 0.f;
        const int e0 = rowoff[lr], e1 = rowoff[lr + 1];
        const int elast = e1 - 1;

        for (int e = e0; e < e1; e += 2) {
            const bool m1 = (e + 1 < e1);
            int c0 = ord[e];
            int c1 = ord[m1 ? e + 1 : elast];
            F16x8U u0, u1;
            u0.v = *(const uint4*)&Hpb[(size_t)c0 * 128 + d * 8];
            u1.v = *(const uint4*)&Hpb[(size_t)c1 * 128 + d * 8];

            float dot0 = dot8(hr2, u0);
            float dot1 = dot8(hr2, u1);

            dot0 += __shfl_xor(dot0, 1);
            dot1 += __shfl_xor(dot1, 1);
            dot0 += __shfl_xor(dot0, 2);
            dot1 += __shfl_xor(dot1, 2);
            dot0 += __shfl_xor(dot0, 4);
            dot1 += __shfl_xor(dot1, 4);
            dot0 += __shfl_xor(dot0, 8);
            dot1 += __shfl_xor(dot1, 8);

            float s0f = fmaxf(dot0, 0.2f * dot0);
            float s1f = fmaxf(dot1, 0.2f * dot1);
            float ex0 = __expf(s0f);
            float ex1 = m1 ? __expf(s1f) : 0.f;
            den += ex0 + ex1;
            #pragma unroll
            for (int k = 0; k < 8; ++k) {
                acc[k] = fmaf((float)u0.h[k], ex0, acc[k]);   // v_fma_mix_f32
                acc[k] = fmaf((float)u1.h[k], ex1, acc[k]);
            }
        }

        float inv = 1.f / (den + 1e-10f);
        float4 o0, o1;
        o0.x = fmaf(acc[0], inv, b0.x);
        o0.y = fmaf(acc[1], inv, b0.y);
        o0.z = fmaf(acc[2], inv, b0.z);
        o0.w = fmaf(acc[3], inv, b0.w);
        o1.x = fmaf(acc[4], inv, b1.x);
        o1.y = fmaf(acc[5], inv, b1.y);
        o1.z = fmaf(acc[6], inv, b1.z);
        o1.w = fmaf(acc[7], inv, b1.w);
        float4* op = (float4*)&out[(size_t)r * 128 + d * 8];
        op[0] = o0;
        op[1] = o1;
    }
}

extern "C" void kernel_launch(void* const* d_in, const int* in_sizes, int n_in,
                              void* d_out, int out_size, void* d_ws, size_t ws_size,
                              hipStream_t stream)
{
    const float* H    = (const float*)d_in[0];
    const float* W    = (const float*)d_in[1];
    const float* bias = (const float*)d_in[2];
    const int*   row  = (const int*)d_in[3];
    const int*   col  = (const int*)d_in[4];
    const int N = in_sizes[0] / 128;
    const int E = in_sizes[3];

    const int nchunk = (E + CHUNK_E - 1) / CHUNK_E;   // 196
    const int nb2    = (N + RPB - 1) / RPB;           // 782

    auto align = [](size_t x) { return (x + 255) & ~(size_t)255; };

    char* ws = (char*)d_ws;
    size_t off = 0;
    unsigned short* Hpb       = (unsigned short*)(ws + off); off = align(off + (size_t)N * 128 * 2);
    unsigned short* Ht        = (unsigned short*)(ws + off); off = align(off + (size_t)nb2 * nchunk * 2);
    unsigned short* rel       = (unsigned short*)(ws + off); off = align(off + (size_t)nb2 * nchunk * 2);
    int*            totals    = (int*)(ws + off);            off = align(off + (size_t)nb2 * 4);
    int*            bucketptr = (int*)(ws + off);            off = align(off + (size_t)(nb2 + 1) * 4);
    unsigned int*   WhiG      = (unsigned int*)(ws + off);   off = align(off + 8192 * 4);
    int*            colsort   = (int*)(ws + off);

    const int gemmBlocks = (N + 127) / 128;

    wsplit<<<8, 256, 0, stream>>>(W, WhiG);
    gemm_hist<<<gemmBlocks + nchunk, 512, 0, stream>>>(H, WhiG, Hpb, N,
                                                       row, Ht, E, nchunk, nb2,
                                                       gemmBlocks);
    bucket_scan<<<nb2, 256, 0, stream>>>(Ht, rel, totals, nchunk);
    bucket_ptr_scan<<<1, 1024, 0, stream>>>(totals, bucketptr, nb2);
    chunk_scatter<<<nchunk, 256, 0, stream>>>(row, col, rel, bucketptr,
                                              colsort, E, nchunk, nb2);
    bucket_aggregate<<<nb2, 512, 0, stream>>>(Hpb, bucketptr, colsort, bias,
                                              (float*)d_out, N);
}

// Round 20
// 123.257 us; speedup vs baseline: 1.1112x; 1.1112x over previous
//
#include <hip/hip_runtime.h>
#include <hip/hip_bf16.h>

#define RSH 7                  // 128 rows per bucket
#define RPB (1 << RSH)
#define CSH 17                 // col bits in packed record (N < 131072)
#define CMASK ((1 << CSH) - 1)
#define CHUNK_E 8192           // edges per chunk block
#define CAP 4096               // max records per bucket (mean ~2046, 45 sigma)
#define NBMAX 1024

typedef __attribute__((ext_vector_type(8))) _Float16 f16x8;
typedef __attribute__((ext_vector_type(2))) _Float16 f16x2;
typedef __attribute__((ext_vector_type(4))) float f32x4;

__device__ __forceinline__ unsigned int pack2h(float a, float b) {
    union { _Float16 h[2]; unsigned int u; } c;
    c.h[0] = (_Float16)a; c.h[1] = (_Float16)b;
    return c.u;
}
__device__ __forceinline__ unsigned short f2h_bits(float f) {
    union { _Float16 h; unsigned short u; } c;
    c.h = (_Float16)f;
    return c.u;
}

// ---------- 0. W pre-convert: build the swizzled f16 LDS image once ----------
__global__ __launch_bounds__(256) void wsplit(
    const float* __restrict__ Wg, unsigned int* __restrict__ WhiG)
{
    int task = blockIdx.x * 256 + threadIdx.x;   // 2048 tasks
    if (task >= 2048) return;
    int n  = task & 127;
    int k0 = (task >> 7) * 8;
    unsigned int hi[4];
    #pragma unroll
    for (int j = 0; j < 4; ++j) {
        float w0 = Wg[(size_t)(k0 + 2*j)     * 128 + n];
        float w1 = Wg[(size_t)(k0 + 2*j + 1) * 128 + n];
        hi[j] = pack2h(w0, w1);
    }
    int byte = (k0 * 2) ^ ((n & 7) << 4);
    *(uint4*)((char*)WhiG + n * 256 + byte) = make_uint4(hi[0], hi[1], hi[2], hi[3]);
}

// ---------- 1. fused: GEMM via single-f16 MFMA + chunk_hist ----------
__global__ __launch_bounds__(512) void gemm_hist(
    const float* __restrict__ H, const unsigned int* __restrict__ WhiG,
    unsigned short* __restrict__ Hpb, int N,
    const int* __restrict__ row, unsigned short* __restrict__ Ht,
    int E, int nchunk, int nb2, int gemmBlocks)
{
    __shared__ unsigned short Ahi[128 * 128];   // 32 KB
    __shared__ unsigned short Whi[128 * 128];   // 32 KB (pre-converted image)
    const int tid = threadIdx.x;

    if (blockIdx.x >= gemmBlocks) {
        int* cnt = (int*)Ahi;
        const int c = blockIdx.x - gemmBlocks;
        for (int i = tid; i < nb2; i += 512) cnt[i] = 0;
        __syncthreads();
        const int e0 = c * CHUNK_E;
        const int e1 = min(e0 + CHUNK_E, E);
        for (int e = e0 + tid; e < e1; e += 512)
            atomicAdd(&cnt[row[e] >> RSH], 1);
        __syncthreads();
        for (int i = tid; i < nb2; i += 512)
            Ht[(size_t)i * nchunk + c] = (unsigned short)cnt[i];
        return;
    }

    const int rbase = blockIdx.x * 128;

    // stage pre-converted W: verbatim 32KB copy
    #pragma unroll
    for (int i = 0; i < 4; ++i) {
        int idx = tid + 512 * i;               // 2048 uint4
        ((uint4*)Whi)[idx] = ((const uint4*)WhiG)[idx];
    }
    // stage H rows as f16
    #pragma unroll
    for (int i = 0; i < 8; ++i) {
        int flat = tid + 512 * i;          // 4096 float4-tasks
        int rr = flat >> 5;
        int c4  = (flat & 31) * 4;
        float4 h = make_float4(0.f, 0.f, 0.f, 0.f);
        if (rbase + rr < N)
            h = *(const float4*)&H[(size_t)(rbase + rr) * 128 + c4];
        uint2 vh;
        vh.x = pack2h(h.x, h.y);
        vh.y = pack2h(h.z, h.w);
        int byte = (c4 * 2) ^ ((rr & 7) << 4);
        *(uint2*)((char*)Ahi + rr * 256 + byte) = vh;
    }
    __syncthreads();

    const int wid = tid >> 6, lane = tid & 63;
    const int wm = wid >> 1, wn = wid & 1;
    const int lr = lane & 15, lg = lane >> 4;
    f32x4 acc[2][4] = {};

    #pragma unroll
    for (int ks = 0; ks < 4; ++ks) {
        const int kb = ks * 64 + lg * 16;
        f16x8 ahi[2];
        #pragma unroll
        for (int mi = 0; mi < 2; ++mi) {
            int rr = wm * 32 + mi * 16 + lr;
            int sw = kb ^ ((rr & 7) << 4);
            ahi[mi] = *(const f16x8*)((char*)Ahi + rr * 256 + sw);
        }
        #pragma unroll
        for (int nf = 0; nf < 4; ++nf) {
            int n = wn * 64 + nf * 16 + lr;
            int sw = kb ^ ((n & 7) << 4);
            f16x8 bhi = *(const f16x8*)((char*)Whi + n * 256 + sw);
            #pragma unroll
            for (int mi = 0; mi < 2; ++mi)
                acc[mi][nf] = __builtin_amdgcn_mfma_f32_16x16x32_f16(ahi[mi], bhi, acc[mi][nf], 0, 0, 0);
        }
    }

    #pragma unroll
    for (int mi = 0; mi < 2; ++mi) {
        #pragma unroll
        for (int nf = 0; nf < 4; ++nf) {
            int col = wn * 64 + nf * 16 + lr;
            #pragma unroll
            for (int i = 0; i < 4; ++i) {
                int rr = rbase + wm * 32 + mi * 16 + lg * 4 + i;
                if (rr < N)
                    Hpb[(size_t)rr * 128 + col] = f2h_bits(acc[mi][nf][i]);
            }
        }
    }
}

// ---------- 2b. per-bucket scan over chunks ----------
__global__ __launch_bounds__(256) void bucket_scan(
    const unsigned short* __restrict__ Ht, unsigned short* __restrict__ rel,
    int* __restrict__ totals, int nchunk)
{
    __shared__ int s[256];
    const int b = blockIdx.x, tid = threadIdx.x;
    int v = (tid < nchunk) ? (int)Ht[(size_t)b * nchunk + tid] : 0;
    s[tid] = v;
    __syncthreads();
    for (int d = 1; d < 256; d <<= 1) {
        int t = (tid >= d) ? s[tid - d] : 0;
        __syncthreads();
        s[tid] += t;
        __syncthreads();
    }
    if (tid < nchunk) rel[(size_t)b * nchunk + tid] = (unsigned short)(s[tid] - v);
    if (tid == 255) totals[b] = s[255];
}

// ---------- 2c. scan bucket totals -> bucketptr ----------
__global__ __launch_bounds__(1024) void bucket_ptr_scan(
    const int* __restrict__ totals, int* __restrict__ bucketptr, int nb2)
{
    __shared__ int s[1024];
    const int tid = threadIdx.x;
    int v = (tid < nb2) ? totals[tid] : 0;
    s[tid] = v;
    __syncthreads();
    for (int d = 1; d < 1024; d <<= 1) {
        int t = (tid >= d) ? s[tid - d] : 0;
        __syncthreads();
        s[tid] += t;
        __syncthreads();
    }
    if (tid < nb2) bucketptr[tid] = s[tid] - v;
    if (tid == nb2 - 1) bucketptr[nb2] = s[tid];
}

// ---------- 2d. single-pass scatter: exact per-chunk offsets, 8KB LDS ----------
__global__ __launch_bounds__(256) void chunk_scatter(
    const int* __restrict__ row, const int* __restrict__ col,
    const unsigned short* __restrict__ rel, const int* __restrict__ bucketptr,
    int* __restrict__ colsort, int E, int nchunk, int nb2)
{
    __shared__ int cur[NBMAX];
    __shared__ int gb[NBMAX];
    const int tid = threadIdx.x;
    const int c = blockIdx.x;
    const int e0 = c * CHUNK_E;
    const int tot = min(CHUNK_E, E - e0);

    for (int b = tid; b < nb2; b += 256) {
        cur[b] = 0;
        gb[b] = bucketptr[b] + (int)rel[(size_t)b * nchunk + c];
    }
    __syncthreads();

    for (int j = tid; j < tot; j += 256) {
        int r = row[e0 + j], cc = col[e0 + j];
        int b = r >> RSH;
        int p = atomicAdd(&cur[b], 1);
        colsort[gb[b] + p] = ((r & (RPB - 1)) << CSH) | cc;
    }
}

// ---------- 2e. per-bucket: derive rowptr + in-place row sort ----------
__global__ __launch_bounds__(256) void bucket_sort(
    const int* __restrict__ bucketptr, int* __restrict__ rowptr,
    int* __restrict__ colsort, int N)
{
    __shared__ int rcnt[RPB];
    __shared__ int rcur[RPB];
    __shared__ int sc[256];
    __shared__ int ord[CAP];
    const int b = blockIdx.x, tid = threadIdx.x;
    const int rbase = b << RSH;
    const int s0 = bucketptr[b];
    const int cnt = bucketptr[b + 1] - s0;

    if (tid < RPB) rcnt[tid] = 0;
    __syncthreads();
    for (int j = tid; j < cnt; j += 256)
        atomicAdd(&rcnt[colsort[s0 + j] >> CSH], 1);
    __syncthreads();

    int v = (tid < RPB) ? rcnt[tid] : 0;
    sc[tid] = v;
    __syncthreads();
    for (int d = 1; d < RPB; d <<= 1) {
        int t = (tid >= d) ? sc[tid - d] : 0;
        __syncthreads();
        sc[tid] += t;
        __syncthreads();
    }
    if (tid < RPB) {
        int ex = sc[tid] - v;
        rcur[tid] = ex;
        int r = rbase + tid;
        if (r < N) rowptr[r] = s0 + ex;
    }
    if (tid == RPB - 1) {
        int rend = min(rbase + RPB, N);
        rowptr[rend] = s0 + cnt;
    }
    __syncthreads();

    for (int j = tid; j < cnt; j += 256) {
        int rec = colsort[s0 + j];
        int p = atomicAdd(&rcur[rec >> CSH], 1);
        ord[p] = rec & CMASK;
    }
    __syncthreads();
    for (int j = tid; j < cnt; j += 256)
        colsort[s0 + j] = ord[j];
}

// ---------- 3. fused score + softmax + aggregate (f16 gathers, fdot2) ----------
union F16x8U {
    uint4 v;
    f16x2 p[4];
    _Float16 h[8];
};

__device__ __forceinline__ float dot8(const f16x2* a, const F16x8U& b) {
#if __has_builtin(__builtin_amdgcn_fdot2)
    float d = __builtin_amdgcn_fdot2(a[0], b.p[0], 0.f, false);
    d = __builtin_amdgcn_fdot2(a[1], b.p[1], d, false);
    d = __builtin_amdgcn_fdot2(a[2], b.p[2], d, false);
    d = __builtin_amdgcn_fdot2(a[3], b.p[3], d, false);
    return d;
#else
    float d = 0.f;
    #pragma unroll
    for (int k = 0; k < 8; ++k)
        d = fmaf((float)a[k >> 1][k & 1], (float)b.h[k], d);
    return d;
#endif
}

__global__ __launch_bounds__(256) void aggregate_kernel(
    const unsigned short* __restrict__ Hpb, const int* __restrict__ rowptr,
    const int* __restrict__ cols, const float* __restrict__ bias,
    float* __restrict__ out, int N)
{
    const int lane = threadIdx.x & 63;
    const int wv   = threadIdx.x >> 6;
    const int r = blockIdx.x * 4 + wv;
    if (r >= N) return;
    const int d = lane & 15;
    const int g = lane >> 4;

    const float4* bp = (const float4*)&bias[d * 8];
    const float4 b0 = bp[0], b1 = bp[1];

    F16x8U hru;
    hru.v = *(const uint4*)&Hpb[(size_t)r * 128 + d * 8];
    f16x2 hr2[4] = {hru.p[0], hru.p[1], hru.p[2], hru.p[3]};

    float acc[8] = {0.f,0.f,0.f,0.f,0.f,0.f,0.f,0.f};
    float den = 0.f;
    const int e0 = rowptr[r], e1 = rowptr[r + 1];
    const int elast = e1 - 1;

    for (int e = e0 + g; e < e1; e += 8) {
        const bool m1 = (e + 4 < e1);
        const int eb = m1 ? e + 4 : elast;
        int c0 = cols[e];
        int c1 = cols[eb];
        F16x8U u0, u1;
        u0.v = *(const uint4*)&Hpb[(size_t)c0 * 128 + d * 8];
        u1.v = *(const uint4*)&Hpb[(size_t)c1 * 128 + d * 8];

        float dot0 = dot8(hr2, u0);
        float dot1 = dot8(hr2, u1);

        dot0 += __shfl_xor(dot0, 1);
        dot1 += __shfl_xor(dot1, 1);
        dot0 += __shfl_xor(dot0, 2);
        dot1 += __shfl_xor(dot1, 2);
        dot0 += __shfl_xor(dot0, 4);
        dot1 += __shfl_xor(dot1, 4);
        dot0 += __shfl_xor(dot0, 8);
        dot1 += __shfl_xor(dot1, 8);

        float s0 = fmaxf(dot0, 0.2f * dot0);
        float s1 = fmaxf(dot1, 0.2f * dot1);
        float ex0 = __expf(s0);
        float ex1 = m1 ? __expf(s1) : 0.f;
        den += ex0 + ex1;
        #pragma unroll
        for (int k = 0; k < 8; ++k) {
            acc[k] = fmaf((float)u0.h[k], ex0, acc[k]);   // v_fma_mix_f32
            acc[k] = fmaf((float)u1.h[k], ex1, acc[k]);
        }
    }

    #pragma unroll
    for (int k = 0; k < 8; ++k) {
        acc[k] += __shfl_xor(acc[k], 16);
        acc[k] += __shfl_xor(acc[k], 32);
    }
    den += __shfl_xor(den, 16);
    den += __shfl_xor(den, 32);

    if (g == 0) {
        float inv = 1.f / (den + 1e-10f);
        float4 o0, o1;
        o0.x = fmaf(acc[0], inv, b0.x);
        o0.y = fmaf(acc[1], inv, b0.y);
        o0.z = fmaf(acc[2], inv, b0.z);
        o0.w = fmaf(acc[3], inv, b0.w);
        o1.x = fmaf(acc[4], inv, b1.x);
        o1.y = fmaf(acc[5], inv, b1.y);
        o1.z = fmaf(acc[6], inv, b1.z);
        o1.w = fmaf(acc[7], inv, b1.w);
        float4* op = (float4*)&out[(size_t)r * 128 + d * 8];
        op[0] = o0;
        op[1] = o1;
    }
}

extern "C" void kernel_launch(void* const* d_in, const int* in_sizes, int n_in,
                              void* d_out, int out_size, void* d_ws, size_t ws_size,
                              hipStream_t stream)
{
    const float* H    = (const float*)d_in[0];
    const float* W    = (const float*)d_in[1];
    const float* bias = (const float*)d_in[2];
    const int*   row  = (const int*)d_in[3];
    const int*   col  = (const int*)d_in[4];
    const int N = in_sizes[0] / 128;
    const int E = in_sizes[3];

    const int nchunk = (E + CHUNK_E - 1) / CHUNK_E;   // 196
    const int nb2    = (N + RPB - 1) / RPB;           // 782

    auto align = [](size_t x) { return (x + 255) & ~(size_t)255; };

    char* ws = (char*)d_ws;
    size_t off = 0;
    unsigned short* Hpb       = (unsigned short*)(ws + off); off = align(off + (size_t)N * 128 * 2);
    unsigned short* Ht        = (unsigned short*)(ws + off); off = align(off + (size_t)nb2 * nchunk * 2);
    unsigned short* rel       = (unsigned short*)(ws + off); off = align(off + (size_t)nb2 * nchunk * 2);
    int*            totals    = (int*)(ws + off);            off = align(off + (size_t)nb2 * 4);
    int*            bucketptr = (int*)(ws + off);            off = align(off + (size_t)(nb2 + 1) * 4);
    int*            rowptr    = (int*)(ws + off);            off = align(off + (size_t)(N + 1) * 4);
    unsigned int*   WhiG      = (unsigned int*)(ws + off);   off = align(off + 8192 * 4);
    int*            colsort   = (int*)(ws + off);

    const int gemmBlocks = (N + 127) / 128;

    wsplit<<<8, 256, 0, stream>>>(W, WhiG);
    gemm_hist<<<gemmBlocks + nchunk, 512, 0, stream>>>(H, WhiG, Hpb, N,
                                                       row, Ht, E, nchunk, nb2,
                                                       gemmBlocks);
    bucket_scan<<<nb2, 256, 0, stream>>>(Ht, rel, totals, nchunk);
    bucket_ptr_scan<<<1, 1024, 0, stream>>>(totals, bucketptr, nb2);
    chunk_scatter<<<nchunk, 256, 0, stream>>>(row, col, rel, bucketptr,
                                              colsort, E, nchunk, nb2);
    bucket_sort<<<nb2, 256, 0, stream>>>(bucketptr, rowptr, colsort, N);
    aggregate_kernel<<<(N + 3) / 4, 256, 0, stream>>>(Hpb, rowptr, colsort, bias,
                                                      (float*)d_out, N);
}